// Round 1
// baseline (207.181 us; speedup 1.0000x reference)
//
#include <hip/hip_runtime.h>

// Problem constants (from reference)
#define BB   32
#define CC   64
#define HH   224
#define WW   224
#define H2   226
#define W2   226
#define HID  8

constexpr unsigned XHW   = HH * WW;        // 50176 per (b,c) plane of x
constexpr unsigned HW2   = H2 * W2;        // 51076 per (b,c) plane of out
constexpr unsigned NTOT  = BB * CC * HW2;  // 104,603,648 output elements
constexpr unsigned NTOT4 = NTOT / 4;       // 26,150,912 float4s
constexpr unsigned NBORD = BB * CC * HH;   // 458,752 outputs per border

// ---------------------------------------------------------------------------
// Kernel 1: write the entire padded output. Interior <- x, ring <- 0.
// Flat float4 stores (out base is 256B aligned, NTOT % 4 == 0).
// ---------------------------------------------------------------------------
__global__ __launch_bounds__(256) void pad_copy_k(const float* __restrict__ x,
                                                  float* __restrict__ out) {
    unsigned tid = blockIdx.x * 256u + threadIdx.x;
    if (tid >= NTOT4) return;
    unsigned e  = tid * 4u;
    unsigned w  = e % W2;
    unsigned t  = e / W2;
    unsigned h  = t % H2;
    unsigned bc = t / H2;
    float v[4];
#pragma unroll
    for (int j = 0; j < 4; ++j) {
        unsigned hi = h - 1u;  // wraps huge if h==0
        unsigned wi = w - 1u;
        v[j] = (hi < (unsigned)HH && wi < (unsigned)WW)
                   ? x[bc * XHW + hi * (unsigned)WW + wi]
                   : 0.f;
        ++w;
        if (w == W2) { w = 0; ++h; if (h == H2) { h = 0; ++bc; } }
    }
    reinterpret_cast<float4*>(out)[tid] = make_float4(v[0], v[1], v[2], v[3]);
}

// ---------------------------------------------------------------------------
// Shared MLP evaluator: s[2][3] -> scalar, weights from LDS.
// y1 = relu(conv(s,w1)+b1); y2 = relu(w2@y1+b2); y3 = relu(w3@y2+b3)
// ---------------------------------------------------------------------------
__device__ __forceinline__ float mlp_eval(const float s[2][3],
                                          const float* __restrict__ W1,
                                          const float* __restrict__ B1,
                                          const float* __restrict__ W2m,
                                          const float* __restrict__ B2,
                                          const float* __restrict__ W3,
                                          float b3) {
    float y1[HID];
#pragma unroll
    for (int h = 0; h < HID; ++h) {
        float a = B1[h];
#pragma unroll
        for (int r = 0; r < 2; ++r)
#pragma unroll
            for (int k = 0; k < 3; ++k)
                a = fmaf(s[r][k], W1[h * 6 + r * 3 + k], a);
        y1[h] = fmaxf(a, 0.f);
    }
    float y2[HID];
#pragma unroll
    for (int o = 0; o < HID; ++o) {
        float a = B2[o];
#pragma unroll
        for (int h = 0; h < HID; ++h) a = fmaf(y1[h], W2m[o * 8 + h], a);
        y2[o] = fmaxf(a, 0.f);
    }
    float a = b3;
#pragma unroll
    for (int h = 0; h < HID; ++h) a = fmaf(y2[h], W3[h], a);
    return fmaxf(a, 0.f);
}

// Stage one branch's weights into LDS.
__device__ __forceinline__ void load_wts(int t,
                                         const float* w1, const float* b1,
                                         const float* w2, const float* b2,
                                         const float* w3, const float* b3,
                                         float* W1, float* B1, float* W2m,
                                         float* B2, float* W3, float* B3) {
    if (t < 48) W1[t] = w1[t];
    if (t < 64) W2m[t] = w2[t];
    if (t < 8) {
        B1[t] = b1[t];
        B2[t] = b2[t];
        W3[t] = w3[t];
    }
    if (t == 0) B3[0] = b3[0];
}

// ---------------------------------------------------------------------------
// Kernel 2: top (blockIdx.y==0) and bottom (==1) borders.
// Reads x rows {0,1} or {222,223} with zero side padding; writes out rows
// 0 / 225, cols 1..224.
// ---------------------------------------------------------------------------
__global__ __launch_bounds__(256) void border_tb_k(
    const float* __restrict__ x, float* __restrict__ out,
    const float* tw1, const float* tb1, const float* tw2, const float* tb2,
    const float* tw3, const float* tb3,
    const float* bw1, const float* bb1, const float* bw2, const float* bb2,
    const float* bw3, const float* bb3) {
    const bool top = (blockIdx.y == 0);
    const float* w1 = top ? tw1 : bw1;
    const float* b1 = top ? tb1 : bb1;
    const float* w2 = top ? tw2 : bw2;
    const float* b2 = top ? tb2 : bb2;
    const float* w3 = top ? tw3 : bw3;
    const float* b3 = top ? tb3 : bb3;

    __shared__ float W1[48], B1[8], W2m[64], B2[8], W3[8], B3[1];
    load_wts(threadIdx.x, w1, b1, w2, b2, w3, b3, W1, B1, W2m, B2, W3, B3);
    __syncthreads();

    unsigned gid = blockIdx.x * 256u + threadIdx.x;
    if (gid >= NBORD) return;
    unsigned l  = gid % (unsigned)HH;   // output position 0..223
    unsigned bc = gid / (unsigned)HH;

    const unsigned r0 = top ? 0u : (unsigned)(HH - 2);
    float s[2][3];
#pragma unroll
    for (int r = 0; r < 2; ++r)
#pragma unroll
        for (int k = 0; k < 3; ++k) {
            unsigned xc = l + (unsigned)k - 1u;  // padded col l+k, x col = m-1
            s[r][k] = (xc < (unsigned)WW)
                          ? x[bc * XHW + (r0 + (unsigned)r) * (unsigned)WW + xc]
                          : 0.f;
        }
    float res = mlp_eval(s, W1, B1, W2m, B2, W3, B3[0]);
    unsigned orow = top ? 0u : (unsigned)(H2 - 1);
    out[bc * HW2 + orow * (unsigned)W2 + (l + 1u)] = res;
}

// ---------------------------------------------------------------------------
// Kernel 3: left (blockIdx.y==0) and right (==1) borders.
// Reads out cols {1,2} or {223,224}, ALL rows 0..225 (incl. freshly written
// top/bottom rows); writes out cols 0 / 225, rows 1..224.
// ---------------------------------------------------------------------------
__global__ __launch_bounds__(256) void border_lr_k(
    float* __restrict__ out,
    const float* lw1, const float* lb1, const float* lw2, const float* lb2,
    const float* lw3, const float* lb3,
    const float* rw1, const float* rb1, const float* rw2, const float* rb2,
    const float* rw3, const float* rb3) {
    const bool left = (blockIdx.y == 0);
    const float* w1 = left ? lw1 : rw1;
    const float* b1 = left ? lb1 : rb1;
    const float* w2 = left ? lw2 : rw2;
    const float* b2 = left ? lb2 : rb2;
    const float* w3 = left ? lw3 : rw3;
    const float* b3 = left ? lb3 : rb3;

    __shared__ float W1[48], B1[8], W2m[64], B2[8], W3[8], B3[1];
    load_wts(threadIdx.x, w1, b1, w2, b2, w3, b3, W1, B1, W2m, B2, W3, B3);
    __syncthreads();

    unsigned gid = blockIdx.x * 256u + threadIdx.x;
    if (gid >= NBORD) return;
    unsigned l  = gid % (unsigned)HH;   // output row-1: writes row l+1
    unsigned bc = gid / (unsigned)HH;

    const unsigned cbase = left ? 1u : (unsigned)(W2 - 3);  // 1 or 223
    float s[2][3];
#pragma unroll
    for (int r = 0; r < 2; ++r)
#pragma unroll
        for (int k = 0; k < 3; ++k)
            s[r][k] = out[bc * HW2 + (l + (unsigned)k) * (unsigned)W2 +
                          (cbase + (unsigned)r)];
    float res = mlp_eval(s, W1, B1, W2m, B2, W3, B3[0]);
    unsigned ocol = left ? 0u : (unsigned)(W2 - 1);
    out[bc * HW2 + (l + 1u) * (unsigned)W2 + ocol] = res;
}

// ---------------------------------------------------------------------------
extern "C" void kernel_launch(void* const* d_in, const int* in_sizes, int n_in,
                              void* d_out, int out_size, void* d_ws,
                              size_t ws_size, hipStream_t stream) {
    const float* x = (const float*)d_in[0];
    // branch weight pointers: t=1..6, b=7..12, l=13..18, r=19..24
    const float* tw[6]; const float* bw[6]; const float* lw[6]; const float* rw[6];
    for (int i = 0; i < 6; ++i) {
        tw[i] = (const float*)d_in[1 + i];
        bw[i] = (const float*)d_in[7 + i];
        lw[i] = (const float*)d_in[13 + i];
        rw[i] = (const float*)d_in[19 + i];
    }
    float* out = (float*)d_out;

    // 1) full padded copy (dominant memory traffic)
    {
        unsigned blocks = (NTOT4 + 255u) / 256u;  // 102152
        pad_copy_k<<<dim3(blocks), dim3(256), 0, stream>>>(x, out);
    }
    // 2) top + bottom borders (read x only)
    {
        unsigned blocks = (NBORD + 255u) / 256u;  // 1792
        border_tb_k<<<dim3(blocks, 2), dim3(256), 0, stream>>>(
            x, out, tw[0], tw[1], tw[2], tw[3], tw[4], tw[5],
            bw[0], bw[1], bw[2], bw[3], bw[4], bw[5]);
    }
    // 3) left + right borders (read freshly written out, incl. rows 0/225)
    {
        unsigned blocks = (NBORD + 255u) / 256u;
        border_lr_k<<<dim3(blocks, 2), dim3(256), 0, stream>>>(
            out, lw[0], lw[1], lw[2], lw[3], lw[4], lw[5],
            rw[0], rw[1], rw[2], rw[3], rw[4], rw[5]);
    }
}